// Round 6
// baseline (456.163 us; speedup 1.0000x reference)
//
#include <hip/hip_runtime.h>
#include <hip/hip_cooperative_groups.h>
#include <math.h>

namespace cg = cooperative_groups;

#define JB   16384
#define FEPS 1e-9f
#define PADX 72     // LDS row stride (ushorts): 144 B, 16B-aligned, <=2-way banks

// ws float offsets — every region fully written before read, no memset needed
#define WS_BD0   0        // 64
#define WS_BD1   64       // 64
#define WS_C1    128      // 8 : c after iter0
#define WS_CF    136      // 8 : final c
#define WS_UHM   256      // 4096 [j][i][e]
#define WS_UMP   4608     // 512*64 u_mean partials
#define WS_TP0   37376    // 64*8*64 t0 partials [rc][j][d]
#define WS_TP1   70144    // 64*8*64
#define WS_R2    102912   // 16384*8 [rn][j]
#define WS_X7B   233984   // 524288 floats (1M ushorts): bf16 x7, rn-order
#define WS_X7BV  758272   // 524288 floats: bf16 x7, rv-order (output rows)
#define WS_BT    1282560  // 16384 floats (32K ushorts): Bt[n][k], n=j*64+e

typedef short short8 __attribute__((ext_vector_type(8)));
typedef float f32x4  __attribute__((ext_vector_type(4)));

static __device__ inline ushort f2bf(float f) {
  union { float f; unsigned u; } a; a.f = f;
  unsigned u = a.u;
  u += 0x7fffu + ((u >> 16) & 1u);   // RNE
  return (ushort)(u >> 16);
}
static __device__ inline float bf2f(ushort h) {
  union { unsigned u; float f; } c; c.u = ((unsigned)h) << 16;
  return c.f;
}

__global__ __launch_bounds__(256, 4) void k_all(const float* __restrict__ x,
                                                const float* __restrict__ w,
                                                float* __restrict__ out,
                                                float* __restrict__ ws) {
  cg::grid_group grid = cg::this_grid();
  int t = threadIdx.x;
  int blk = blockIdx.x;                 // 512 blocks
  int lane = t & 63, wv = t >> 6;
  int m = lane & 15, quad = lane >> 4;
  int j = blk & 7;                      // (rc, j) decomposition for GEMM phases
  int rc = blk >> 3;                    // 64 row-chunks of 256 rows
  int rm0 = rc * 256;

  __shared__ float4 s4[256];            // 4 KB
  __shared__ ushort x7l[128 * PADX];    // 18 KB
  __shared__ float gs[128];
  __shared__ float red[256];
  __shared__ float t0l[64];
  __shared__ float vml[64];
  __shared__ float bdl[8];

  ushort* x7b  = (ushort*)(ws + WS_X7B);
  ushort* x7bv = (ushort*)(ws + WS_X7BV);
  ushort* bt   = (ushort*)(ws + WS_BT);

  // ================= Phase 1: x scan -> u_mean partials, bf16 x7 (2 copies)
  {
    int i = blk >> 6;
    int rb0 = (blk & 63) * 256;
    int q = t & 15, rsub = t >> 4;
    const float4* xr = (const float4*)(x + ((size_t)i * JB + rb0) * 64);
    float4 a = make_float4(0.f, 0.f, 0.f, 0.f);
    for (int rr = rsub; rr < 256; rr += 16) {
      float4 v = xr[rr * 16 + q];
      a.x += v.x; a.y += v.y; a.z += v.z; a.w += v.w;
      if (i == 7) {                     // uniform branch
        ushort4 h = make_ushort4(f2bf(v.x), f2bf(v.y), f2bf(v.z), f2bf(v.w));
        int rn = rb0 + rr;
        *(ushort4*)(x7b + (size_t)rn * 64 + q * 4) = h;
        int rv = ((rn & 511) << 5) | (rn >> 9);   // rv = s*32 + b
        *(ushort4*)(x7bv + (size_t)rv * 64 + q * 4) = h;
      }
    }
    s4[t] = a;
    __syncthreads();
    if (t < 16) {
      float4 s = s4[t];
      for (int k = 1; k < 16; ++k) {
        float4 v = s4[t + k * 16];
        s.x += v.x; s.y += v.y; s.z += v.z; s.w += v.w;
      }
      *(float4*)(ws + WS_UMP + (size_t)blk * 64 + t * 4) = s;
    }
  }
  grid.sync();

  // ================= Phase 2: u_mean reduce + uhm + bt  (blocks 0..63)
  if (blk < 64) {
    int i2 = blk >> 3, j2 = blk & 7;
    #pragma unroll
    for (int p = 0; p < 2; ++p) {
      int local = t + p * 256;
      int eo = local >> 6, k = local & 63;
      int e = i2 * 8 + eo;
      bt[(size_t)(j2 * 64 + e) * 64 + k] = f2bf(w[(size_t)(56 + j2) * 4096 + k * 64 + e]);
    }
    if (t < 64) {
      const float* up = ws + WS_UMP + (size_t)(i2 * 64) * 64 + t;
      float s = 0.f;
      #pragma unroll 8
      for (int c = 0; c < 64; ++c) s += up[c * 64];
      t0l[t] = s;
    }
    __syncthreads();
    if (t < 64) {
      const float* wij = w + (size_t)((i2 * 8 + j2) * 64) * 64;
      float acc = 0.f;
      for (int d = 0; d < 64; ++d) acc += wij[d * 64 + t] * t0l[d];
      ws[WS_UHM + (size_t)(j2 * 8 + i2) * 64 + t] = acc * (1.0f / (float)JB);
    }
  }
  grid.sync();

  // ================= Phase 3: MFMA GEMM -> r2 + (c0=1/8) t0 partials
  {
    short8 bfr[4][2];
    const ushort* btj = bt + (size_t)(j * 64) * 64;
    #pragma unroll
    for (int nt = 0; nt < 4; ++nt)
      #pragma unroll
      for (int kb = 0; kb < 2; ++kb)
        bfr[nt][kb] = *(const short8*)(btj + (size_t)(nt * 16 + m) * 64 + kb * 32 + quad * 8);

    float tacc = 0.f;                   // thread = (wv, d=lane)
    #pragma unroll
    for (int h = 0; h < 2; ++h) {
      int rbh = rm0 + h * 128;
      #pragma unroll
      for (int s = 0; s < 2; ++s) {
        int rb = rbh + s * 64 + wv * 16;
        const ushort* ap = x7b + (size_t)(rb + m) * 64 + quad * 8;
        short8 a0 = *(const short8*)ap;
        short8 a1 = *(const short8*)(ap + 32);
        int lrow = s * 64 + wv * 16 + m;
        *(short8*)(x7l + lrow * PADX + quad * 8) = a0;       // stage for t0 wsum
        *(short8*)(x7l + lrow * PADX + 32 + quad * 8) = a1;
        f32x4 acc[4];
        #pragma unroll
        for (int nt = 0; nt < 4; ++nt) acc[nt] = (f32x4){0.f, 0.f, 0.f, 0.f};
        #pragma unroll
        for (int nt = 0; nt < 4; ++nt) {
          acc[nt] = __builtin_amdgcn_mfma_f32_16x16x32_bf16(a0, bfr[nt][0], acc[nt], 0, 0, 0);
          acc[nt] = __builtin_amdgcn_mfma_f32_16x16x32_bf16(a1, bfr[nt][1], acc[nt], 0, 0, 0);
        }
        float sq[4];
        #pragma unroll
        for (int r = 0; r < 4; ++r)
          sq[r] = acc[0][r] * acc[0][r] + acc[1][r] * acc[1][r] +
                  acc[2][r] * acc[2][r] + acc[3][r] * acc[3][r];
        #pragma unroll
        for (int mk = 1; mk < 16; mk <<= 1) {
          #pragma unroll
          for (int r = 0; r < 4; ++r) sq[r] += __shfl_xor(sq[r], mk, 64);
        }
        if (m == 0) {
          #pragma unroll
          for (int r = 0; r < 4; ++r) {
            int row = rb + quad * 4 + r;
            ws[WS_R2 + (size_t)row * 8 + j] = sq[r];
            float s2 = 0.015625f * sq[r];           // (1/8)^2 * r2
            gs[s * 64 + wv * 16 + quad * 4 + r] =
                0.125f * s2 / ((1.f + s2) * sqrtf(s2 + FEPS));
          }
        }
      }
      __syncthreads();
      {
        int d = lane;
        float a = 0.f;
        #pragma unroll 8
        for (int r = 0; r < 32; ++r) {
          int row = wv * 32 + r;
          a += gs[row] * bf2f(x7l[row * PADX + d]);
        }
        tacc += a;
      }
      __syncthreads();
    }
    red[t] = tacc;
    __syncthreads();
    if (t < 64)
      ws[WS_TP0 + (size_t)(rc * 8 + j) * 64 + t] =
          red[t] + red[t + 64] + red[t + 128] + red[t + 192];
  }
  grid.sync();

  // ================= Phase 4: t0 -> vm -> Bd0, c1   (blocks 0..7)
  if (blk < 8) {
    int jj = blk;
    {
      int d = t & 63, qtr = t >> 6;
      const float* tp = ws + WS_TP0;
      float s = 0.f;
      for (int rr = qtr * 16; rr < qtr * 16 + 16; ++rr)
        s += tp[(size_t)(rr * 8 + jj) * 64 + d];
      red[t] = s;
    }
    __syncthreads();
    if (t < 64) t0l[t] = red[t] + red[t + 64] + red[t + 128] + red[t + 192];
    __syncthreads();
    if (t < 64) {
      const float* w7j = w + (size_t)((56 + jj) * 64) * 64;
      float acc = 0.f;
      for (int d = 0; d < 64; ++d) acc += w7j[d * 64 + t] * t0l[d];
      vml[t] = acc * (1.0f / (float)JB);
    }
    __syncthreads();
    if (t < 8) {
      const float* uhm = ws + WS_UHM + (size_t)(jj * 8 + t) * 64;
      float b = 0.f;
      for (int e = 0; e < 64; ++e) b += uhm[e] * vml[e];
      bdl[t] = b;
      ws[WS_BD0 + t * 8 + jj] = b;
    }
    __syncthreads();
    if (t == 0) {
      float mx = -1e30f;
      for (int i = 0; i < 8; ++i) mx = fmaxf(mx, bdl[i]);
      float ss = 0.f;
      for (int i = 0; i < 8; ++i) ss += expf(bdl[i] - mx);
      ws[WS_C1 + jj] = expf(bdl[7] - mx) / ss;
    }
  }
  grid.sync();

  // ================= Phase 5: t1 partials (uses c1, r2, bf16 x7)
  {
    float c1 = ws[WS_C1 + j];
    float tacc = 0.f;
    #pragma unroll
    for (int h = 0; h < 2; ++h) {
      int rbh = rm0 + h * 128;
      #pragma unroll
      for (int k = 0; k < 4; ++k) {
        int c16 = t + k * 256;
        int row = c16 >> 3, seg = c16 & 7;
        short8 v = *(const short8*)(x7b + (size_t)(rbh + row) * 64 + seg * 8);
        *(short8*)(x7l + row * PADX + seg * 8) = v;
      }
      if (t < 128) {
        float r2v = ws[WS_R2 + (size_t)(rbh + t) * 8 + j];
        float s2 = c1 * c1 * r2v;
        gs[t] = c1 * s2 / ((1.f + s2) * sqrtf(s2 + FEPS));
      }
      __syncthreads();
      {
        int d = lane;
        float a = 0.f;
        #pragma unroll 8
        for (int r = 0; r < 32; ++r) {
          int row = wv * 32 + r;
          a += gs[row] * bf2f(x7l[row * PADX + d]);
        }
        tacc += a;
      }
      __syncthreads();
    }
    red[t] = tacc;
    __syncthreads();
    if (t < 64)
      ws[WS_TP1 + (size_t)(rc * 8 + j) * 64 + t] =
          red[t] + red[t + 64] + red[t + 128] + red[t + 192];
  }
  grid.sync();

  // ================= Phase 6: t1 -> vm -> Bd1, cf   (blocks 0..7)
  if (blk < 8) {
    int jj = blk;
    {
      int d = t & 63, qtr = t >> 6;
      const float* tp = ws + WS_TP1;
      float s = 0.f;
      for (int rr = qtr * 16; rr < qtr * 16 + 16; ++rr)
        s += tp[(size_t)(rr * 8 + jj) * 64 + d];
      red[t] = s;
    }
    __syncthreads();
    if (t < 64) t0l[t] = red[t] + red[t + 64] + red[t + 128] + red[t + 192];
    __syncthreads();
    if (t < 64) {
      const float* w7j = w + (size_t)((56 + jj) * 64) * 64;
      float acc = 0.f;
      for (int d = 0; d < 64; ++d) acc += w7j[d * 64 + t] * t0l[d];
      vml[t] = acc * (1.0f / (float)JB);
    }
    __syncthreads();
    if (t < 8) {
      const float* uhm = ws + WS_UHM + (size_t)(jj * 8 + t) * 64;
      float b = 0.f;
      for (int e = 0; e < 64; ++e) b += uhm[e] * vml[e];
      ws[WS_BD1 + t * 8 + jj] = b;
      bdl[t] = ws[WS_BD0 + t * 8 + jj] + b;
    }
    __syncthreads();
    if (t == 0) {
      float mx = -1e30f;
      for (int i = 0; i < 8; ++i) mx = fmaxf(mx, bdl[i]);
      float ss = 0.f;
      for (int i = 0; i < 8; ++i) ss += expf(bdl[i] - mx);
      ws[WS_CF + jj] = expf(bdl[7] - mx) / ss;
    }
  }
  grid.sync();

  // ================= Phase 7: final MFMA GEMM (rv-order) -> out
  {
    float cf = ws[WS_CF + j];
    short8 bfr[4][2];
    const ushort* btj = bt + (size_t)(j * 64) * 64;
    #pragma unroll
    for (int nt = 0; nt < 4; ++nt)
      #pragma unroll
      for (int kb = 0; kb < 2; ++kb)
        bfr[nt][kb] = *(const short8*)(btj + (size_t)(nt * 16 + m) * 64 + kb * 32 + quad * 8);
    #pragma unroll
    for (int h = 0; h < 2; ++h) {
      #pragma unroll
      for (int s = 0; s < 2; ++s) {
        int rb = rm0 + h * 128 + s * 64 + wv * 16;   // rv-order rows
        const ushort* ap = x7bv + (size_t)(rb + m) * 64 + quad * 8;
        short8 a0 = *(const short8*)ap;
        short8 a1 = *(const short8*)(ap + 32);
        f32x4 acc[4];
        #pragma unroll
        for (int nt = 0; nt < 4; ++nt) acc[nt] = (f32x4){0.f, 0.f, 0.f, 0.f};
        #pragma unroll
        for (int nt = 0; nt < 4; ++nt) {
          acc[nt] = __builtin_amdgcn_mfma_f32_16x16x32_bf16(a0, bfr[nt][0], acc[nt], 0, 0, 0);
          acc[nt] = __builtin_amdgcn_mfma_f32_16x16x32_bf16(a1, bfr[nt][1], acc[nt], 0, 0, 0);
        }
        float sq[4];
        #pragma unroll
        for (int r = 0; r < 4; ++r)
          sq[r] = acc[0][r] * acc[0][r] + acc[1][r] * acc[1][r] +
                  acc[2][r] * acc[2][r] + acc[3][r] * acc[3][r];
        #pragma unroll
        for (int mk = 1; mk < 16; mk <<= 1) {
          #pragma unroll
          for (int r = 0; r < 4; ++r) sq[r] += __shfl_xor(sq[r], mk, 64);
        }
        #pragma unroll
        for (int r = 0; r < 4; ++r) {
          float s2 = cf * cf * sq[r];
          float g = cf * s2 / ((1.f + s2) * sqrtf(s2 + FEPS));
          size_t base = ((size_t)j * JB + (rb + quad * 4 + r)) * 64;
          #pragma unroll
          for (int nt = 0; nt < 4; ++nt)
            out[base + nt * 16 + m] = g * acc[nt][r];
        }
      }
    }
  }
}

extern "C" void kernel_launch(void* const* d_in, const int* in_sizes, int n_in,
                              void* d_out, int out_size, void* d_ws, size_t ws_size,
                              hipStream_t stream) {
  const float* x = (const float*)d_in[0];   // (8,32,512,64) f32
  const float* w = (const float*)d_in[1];   // (8,8,64,64)  f32
  float* out = (float*)d_out;               // (8,32,512,64) f32
  float* ws = (float*)d_ws;

  void* args[] = { (void*)&x, (void*)&w, (void*)&out, (void*)&ws };
  hipLaunchCooperativeKernel((void*)k_all, dim3(512), dim3(256), args, 0, stream);
}

// Round 7
// 209.837 us; speedup vs baseline: 2.1739x; 2.1739x over previous
//
#include <hip/hip_runtime.h>
#include <math.h>

#define JB   16384
#define FEPS 1e-9f
#define PADX 72     // LDS row stride (ushorts): 144 B, 16B-aligned, <=2-way banks

// ws float offsets — counters zeroed by 64-B memset; rest fully written before read
#define WS_CNT   0        // 2 uints used (ticket counters K2, K3); 16 floats reserved
#define WS_C1    16       // 8 : c after iter0
#define WS_CF    24       // 8 : final c
#define WS_BD0   32       // 64 : B-delta iter 0 [i*8+j]
#define WS_UHM   128      // 4096 [j][i][e], normalized (1/JB)
#define WS_UMP   4608     // 256*64 u_mean partials [i*32+c][64]
#define WS_TP0   20992    // 64*8*64 t0 partials [rc][j][d]
#define WS_TP1   53760    // 64*8*64 t1 partials
#define WS_R2    86528    // 16384*8 [rn][j]
#define WS_X7B   217600   // 524288 fl (1M ushorts): bf16 x7, rn-order
#define WS_X7BV  741888   // 524288 fl: bf16 x7, rv-order (output rows)
#define WS_BT    1266176  // 16384 fl (32K ushorts): Bt[n][k], n=j*64+e

typedef short short8 __attribute__((ext_vector_type(8)));
typedef float f32x4  __attribute__((ext_vector_type(4)));

static __device__ inline ushort f2bf(float f) {
  union { float f; unsigned u; } a; a.f = f;
  unsigned u = a.u;
  u += 0x7fffu + ((u >> 16) & 1u);   // RNE
  return (ushort)(u >> 16);
}
static __device__ inline float bf2f(ushort h) {
  union { unsigned u; float f; } c; c.u = ((unsigned)h) << 16;
  return c.f;
}

// ---------------------------------------------------------------- K1: prep
// u_mean partials; bf16 x7 in rn-order and rv-order; bt (blocks 0..7)
__global__ __launch_bounds__(256) void k_prep(const float* __restrict__ x,
                                              const float* __restrict__ w,
                                              float* __restrict__ ws) {
  int blk = blockIdx.x;          // 256 blocks: i (8) x chunk (32)
  int i = blk >> 5, c32 = blk & 31;
  int t = threadIdx.x;
  int q = t & 15, rsub = t >> 4;
  const float4* xr = reinterpret_cast<const float4*>(x) +
                     (size_t)(i * JB + c32 * 512) * 16;
  ushort* x7b  = (ushort*)(ws + WS_X7B);
  ushort* x7bv = (ushort*)(ws + WS_X7BV);
  float4 a = make_float4(0.f, 0.f, 0.f, 0.f);
  for (int rr = rsub; rr < 512; rr += 16) {
    float4 v = xr[rr * 16 + q];
    a.x += v.x; a.y += v.y; a.z += v.z; a.w += v.w;
    if (i == 7) {                // uniform branch
      ushort4 h = make_ushort4(f2bf(v.x), f2bf(v.y), f2bf(v.z), f2bf(v.w));
      int rn = c32 * 512 + rr;
      *(ushort4*)(x7b + (size_t)rn * 64 + q * 4) = h;
      int rv = ((rn & 511) << 5) | (rn >> 9);   // rv = s*32 + b
      *(ushort4*)(x7bv + (size_t)rv * 64 + q * 4) = h;
    }
  }
  __shared__ float4 s4[256];
  s4[t] = a;
  __syncthreads();
  if (t < 16) {
    float4 s = s4[t];
    for (int k = 1; k < 16; ++k) {
      float4 v = s4[t + k * 16];
      s.x += v.x; s.y += v.y; s.z += v.z; s.w += v.w;
    }
    *(float4*)(ws + WS_UMP + (size_t)blk * 64 + t * 4) = s;
  }
  // bt build: blocks 0..7 (j = blk), via LDS transpose, coalesced both ways
  if (blk < 8) {
    __shared__ float wl[4096];
    int jj = blk;
    #pragma unroll
    for (int k = 0; k < 16; ++k) {
      int f = t + k * 256;
      wl[f] = w[(size_t)(56 + jj) * 4096 + f];   // wl[d*64+e]
    }
    __syncthreads();
    ushort* bt = (ushort*)(ws + WS_BT);
    #pragma unroll
    for (int k = 0; k < 4; ++k) {
      int flat = t + k * 256;                    // 0..1023
      int e = flat >> 4, dq = flat & 15;
      ushort4 hh = make_ushort4(f2bf(wl[(dq * 4 + 0) * 64 + e]),
                                f2bf(wl[(dq * 4 + 1) * 64 + e]),
                                f2bf(wl[(dq * 4 + 2) * 64 + e]),
                                f2bf(wl[(dq * 4 + 3) * 64 + e]));
      *(ushort4*)(bt + (size_t)(jj * 64 + e) * 64 + dq * 4) = hh;
    }
  }
}

// ---------------------------------------------------------------- K2
// MFMA GEMM -> r2 + t0 partials (c0 = 1/8). Blocks (rc 0..63, j 0..7), 256 rows.
// Blocks 0..63 also compute uhm. Last block: t0 -> vm -> Bd0 -> c1.
__global__ __launch_bounds__(256) void k_r2t0(const float* __restrict__ w,
                                              float* __restrict__ ws) {
  int t = threadIdx.x, blk = blockIdx.x;
  int lane = t & 63, wv = t >> 6, m = lane & 15, quad = lane >> 4;
  int j = blk & 7, rc = blk >> 3, rm0 = rc * 256;
  __shared__ ushort x7l[128 * PADX];   // 18 KB (aliased as wl for uhm)
  __shared__ float gs[128];
  __shared__ float red[256];
  __shared__ float tl[512];
  __shared__ float vml[512];
  __shared__ float bdl[64];
  __shared__ bool amLast;
  ushort* x7b = (ushort*)(ws + WS_X7B);
  ushort* bt  = (ushort*)(ws + WS_BT);

  if (blk < 64) {                      // uhm for (i2=rc, j2=j)
    int i2 = rc, j2 = j;
    float* wl = (float*)x7l;           // 16 KB alias
    #pragma unroll
    for (int k = 0; k < 16; ++k) {
      int f = t + k * 256;
      wl[f] = w[(size_t)(i2 * 8 + j2) * 4096 + f];   // wl[d*64+e]
    }
    if (t < 64) {
      float s = 0.f;
      #pragma unroll 8
      for (int c = 0; c < 32; ++c) s += ws[WS_UMP + (size_t)(i2 * 32 + c) * 64 + t];
      gs[t] = s;                       // um[i2][t]
    }
    __syncthreads();
    if (t < 64) {
      float acc = 0.f;
      for (int d = 0; d < 64; ++d) acc += wl[d * 64 + t] * gs[d];
      ws[WS_UHM + (size_t)(j2 * 8 + i2) * 64 + t] = acc * (1.0f / (float)JB);
    }
    __syncthreads();                   // before x7l/gs reuse
  }

  short8 bfr[4][2];
  const ushort* btj = bt + (size_t)(j * 64) * 64;
  #pragma unroll
  for (int nt = 0; nt < 4; ++nt)
    #pragma unroll
    for (int kb = 0; kb < 2; ++kb)
      bfr[nt][kb] = *(const short8*)(btj + (size_t)(nt * 16 + m) * 64 + kb * 32 + quad * 8);

  float tacc = 0.f;                    // thread = (wv, d=lane)
  #pragma unroll
  for (int h = 0; h < 2; ++h) {
    int rbh = rm0 + h * 128;
    #pragma unroll
    for (int s = 0; s < 2; ++s) {
      int rb = rbh + s * 64 + wv * 16;
      const ushort* ap = x7b + (size_t)(rb + m) * 64 + quad * 8;
      short8 a0 = *(const short8*)ap;
      short8 a1 = *(const short8*)(ap + 32);
      int lrow = s * 64 + wv * 16 + m;
      *(short8*)(x7l + lrow * PADX + quad * 8) = a0;        // stage for t0
      *(short8*)(x7l + lrow * PADX + 32 + quad * 8) = a1;
      f32x4 acc[4];
      #pragma unroll
      for (int nt = 0; nt < 4; ++nt) acc[nt] = (f32x4){0.f, 0.f, 0.f, 0.f};
      #pragma unroll
      for (int nt = 0; nt < 4; ++nt) {
        acc[nt] = __builtin_amdgcn_mfma_f32_16x16x32_bf16(a0, bfr[nt][0], acc[nt], 0, 0, 0);
        acc[nt] = __builtin_amdgcn_mfma_f32_16x16x32_bf16(a1, bfr[nt][1], acc[nt], 0, 0, 0);
      }
      float sq[4];
      #pragma unroll
      for (int r = 0; r < 4; ++r)
        sq[r] = acc[0][r] * acc[0][r] + acc[1][r] * acc[1][r] +
                acc[2][r] * acc[2][r] + acc[3][r] * acc[3][r];
      #pragma unroll
      for (int mk = 1; mk < 16; mk <<= 1) {
        #pragma unroll
        for (int r = 0; r < 4; ++r) sq[r] += __shfl_xor(sq[r], mk, 64);
      }
      if (m == 0) {
        #pragma unroll
        for (int r = 0; r < 4; ++r) {
          int row = rb + quad * 4 + r;
          ws[WS_R2 + (size_t)row * 8 + j] = sq[r];
          float s2 = 0.015625f * sq[r];              // (1/8)^2 * r2
          gs[s * 64 + wv * 16 + quad * 4 + r] =
              0.125f * s2 / ((1.f + s2) * sqrtf(s2 + FEPS));
        }
      }
    }
    __syncthreads();
    {
      int d = lane;
      float a = 0.f;
      #pragma unroll 8
      for (int r = 0; r < 32; ++r) {
        int row = wv * 32 + r;
        a += gs[row] * bf2f(x7l[row * PADX + d]);
      }
      tacc += a;
    }
    __syncthreads();
  }
  red[t] = tacc;
  __syncthreads();
  if (t < 64)
    ws[WS_TP0 + (size_t)(rc * 8 + j) * 64 + t] =
        red[t] + red[t + 64] + red[t + 128] + red[t + 192];

  // -------- last-block: t0 -> vm -> Bd0 -> c1
  __threadfence();
  if (t == 0) amLast = (atomicAdd((unsigned int*)ws + 0, 1u) == 511u);
  __syncthreads();
  if (!amLast) return;
  __threadfence();
  #pragma unroll
  for (int u = 0; u < 2; ++u) {
    int idx = t + u * 256, jj = idx >> 6, dd = idx & 63;
    float s = 0.f;
    #pragma unroll 8
    for (int r = 0; r < 64; ++r) s += ws[WS_TP0 + (size_t)(r * 8 + jj) * 64 + dd];
    tl[idx] = s;
  }
  __syncthreads();
  #pragma unroll
  for (int u = 0; u < 2; ++u) {
    int idx = t + u * 256, jj = idx >> 6, e = idx & 63;
    const float* w7j = w + (size_t)(56 + jj) * 4096;
    float acc = 0.f;
    for (int d = 0; d < 64; ++d) acc += w7j[d * 64 + e] * tl[jj * 64 + d];
    vml[idx] = acc * (1.0f / (float)JB);
  }
  __syncthreads();
  if (t < 64) {
    int i3 = t >> 3, j3 = t & 7;
    const float* uhm = ws + WS_UHM + (size_t)(j3 * 8 + i3) * 64;
    float b = 0.f;
    for (int e = 0; e < 64; ++e) b += uhm[e] * vml[j3 * 64 + e];
    bdl[t] = b;                        // bdl[i*8+j]
    ws[WS_BD0 + t] = b;
  }
  __syncthreads();
  if (t < 8) {
    float mx = -1e30f;
    for (int i = 0; i < 8; ++i) mx = fmaxf(mx, bdl[i * 8 + t]);
    float ss = 0.f;
    for (int i = 0; i < 8; ++i) ss += expf(bdl[i * 8 + t] - mx);
    ws[WS_C1 + t] = expf(bdl[56 + t] - mx) / ss;
  }
}

// ---------------------------------------------------------------- K3
// t1 partials from bf16 x7 + stored r2 (uses c1). Last block: Bd1 -> cf.
__global__ __launch_bounds__(256) void k_t1(const float* __restrict__ w,
                                            float* __restrict__ ws) {
  int t = threadIdx.x, blk = blockIdx.x;
  int lane = t & 63, wv = t >> 6;
  int j = blk & 7, rc = blk >> 3, rm0 = rc * 256;
  __shared__ ushort x7l[128 * PADX];
  __shared__ float gs[128];
  __shared__ float red[256];
  __shared__ float tl[512];
  __shared__ float vml[512];
  __shared__ float bdl[64];
  __shared__ bool amLast;
  ushort* x7b = (ushort*)(ws + WS_X7B);

  float c1 = ws[WS_C1 + j];
  float tacc = 0.f;
  #pragma unroll
  for (int h = 0; h < 2; ++h) {
    int rbh = rm0 + h * 128;
    #pragma unroll
    for (int k = 0; k < 4; ++k) {
      int c16 = t + k * 256;
      int row = c16 >> 3, seg = c16 & 7;
      *(short8*)(x7l + row * PADX + seg * 8) =
          *(const short8*)(x7b + (size_t)(rbh + row) * 64 + seg * 8);
    }
    if (t < 128) {
      float r2v = ws[WS_R2 + (size_t)(rbh + t) * 8 + j];
      float s2 = c1 * c1 * r2v;
      gs[t] = c1 * s2 / ((1.f + s2) * sqrtf(s2 + FEPS));
    }
    __syncthreads();
    {
      int d = lane;
      float a = 0.f;
      #pragma unroll 8
      for (int r = 0; r < 32; ++r) {
        int row = wv * 32 + r;
        a += gs[row] * bf2f(x7l[row * PADX + d]);
      }
      tacc += a;
    }
    __syncthreads();
  }
  red[t] = tacc;
  __syncthreads();
  if (t < 64)
    ws[WS_TP1 + (size_t)(rc * 8 + j) * 64 + t] =
        red[t] + red[t + 64] + red[t + 128] + red[t + 192];

  // -------- last-block: t1 -> vm -> Bd1 -> cf
  __threadfence();
  if (t == 0) amLast = (atomicAdd((unsigned int*)ws + 1, 1u) == 511u);
  __syncthreads();
  if (!amLast) return;
  __threadfence();
  #pragma unroll
  for (int u = 0; u < 2; ++u) {
    int idx = t + u * 256, jj = idx >> 6, dd = idx & 63;
    float s = 0.f;
    #pragma unroll 8
    for (int r = 0; r < 64; ++r) s += ws[WS_TP1 + (size_t)(r * 8 + jj) * 64 + dd];
    tl[idx] = s;
  }
  __syncthreads();
  #pragma unroll
  for (int u = 0; u < 2; ++u) {
    int idx = t + u * 256, jj = idx >> 6, e = idx & 63;
    const float* w7j = w + (size_t)(56 + jj) * 4096;
    float acc = 0.f;
    for (int d = 0; d < 64; ++d) acc += w7j[d * 64 + e] * tl[jj * 64 + d];
    vml[idx] = acc * (1.0f / (float)JB);
  }
  __syncthreads();
  if (t < 64) {
    int i3 = t >> 3, j3 = t & 7;
    const float* uhm = ws + WS_UHM + (size_t)(j3 * 8 + i3) * 64;
    float b = 0.f;
    for (int e = 0; e < 64; ++e) b += uhm[e] * vml[j3 * 64 + e];
    bdl[t] = ws[WS_BD0 + t] + b;       // Bd0 + Bd1
  }
  __syncthreads();
  if (t < 8) {
    float mx = -1e30f;
    for (int i = 0; i < 8; ++i) mx = fmaxf(mx, bdl[i * 8 + t]);
    float ss = 0.f;
    for (int i = 0; i < 8; ++i) ss += expf(bdl[i * 8 + t] - mx);
    ws[WS_CF + t] = expf(bdl[56 + t] - mx) / ss;
  }
}

// ---------------------------------------------------------------- K4: final
// out[j][rv][e] = g(cf_j, r2) * p, rv-order rows via x7bv (coalesced A + stores)
__global__ __launch_bounds__(256) void k_final(float* __restrict__ out,
                                               float* __restrict__ ws) {
  int t = threadIdx.x, blk = blockIdx.x;
  int lane = t & 63, wv = t >> 6, m = lane & 15, quad = lane >> 4;
  int j = blk & 7, rc = blk >> 3, rm0 = rc * 256;
  ushort* x7bv = (ushort*)(ws + WS_X7BV);
  ushort* bt   = (ushort*)(ws + WS_BT);
  float cf = ws[WS_CF + j];

  short8 bfr[4][2];
  const ushort* btj = bt + (size_t)(j * 64) * 64;
  #pragma unroll
  for (int nt = 0; nt < 4; ++nt)
    #pragma unroll
    for (int kb = 0; kb < 2; ++kb)
      bfr[nt][kb] = *(const short8*)(btj + (size_t)(nt * 16 + m) * 64 + kb * 32 + quad * 8);

  #pragma unroll
  for (int h = 0; h < 2; ++h) {
    #pragma unroll
    for (int s = 0; s < 2; ++s) {
      int rb = rm0 + h * 128 + s * 64 + wv * 16;   // rv-order rows
      const ushort* ap = x7bv + (size_t)(rb + m) * 64 + quad * 8;
      short8 a0 = *(const short8*)ap;
      short8 a1 = *(const short8*)(ap + 32);
      f32x4 acc[4];
      #pragma unroll
      for (int nt = 0; nt < 4; ++nt) acc[nt] = (f32x4){0.f, 0.f, 0.f, 0.f};
      #pragma unroll
      for (int nt = 0; nt < 4; ++nt) {
        acc[nt] = __builtin_amdgcn_mfma_f32_16x16x32_bf16(a0, bfr[nt][0], acc[nt], 0, 0, 0);
        acc[nt] = __builtin_amdgcn_mfma_f32_16x16x32_bf16(a1, bfr[nt][1], acc[nt], 0, 0, 0);
      }
      float sq[4];
      #pragma unroll
      for (int r = 0; r < 4; ++r)
        sq[r] = acc[0][r] * acc[0][r] + acc[1][r] * acc[1][r] +
                acc[2][r] * acc[2][r] + acc[3][r] * acc[3][r];
      #pragma unroll
      for (int mk = 1; mk < 16; mk <<= 1) {
        #pragma unroll
        for (int r = 0; r < 4; ++r) sq[r] += __shfl_xor(sq[r], mk, 64);
      }
      #pragma unroll
      for (int r = 0; r < 4; ++r) {
        float s2 = cf * cf * sq[r];
        float g = cf * s2 / ((1.f + s2) * sqrtf(s2 + FEPS));
        size_t base = ((size_t)j * JB + (rb + quad * 4 + r)) * 64;
        #pragma unroll
        for (int nt = 0; nt < 4; ++nt)
          out[base + nt * 16 + m] = g * acc[nt][r];
      }
    }
  }
}

extern "C" void kernel_launch(void* const* d_in, const int* in_sizes, int n_in,
                              void* d_out, int out_size, void* d_ws, size_t ws_size,
                              hipStream_t stream) {
  const float* x = (const float*)d_in[0];   // (8,32,512,64) f32
  const float* w = (const float*)d_in[1];   // (8,8,64,64)  f32
  float* out = (float*)d_out;               // (8,32,512,64) f32
  float* ws = (float*)d_ws;

  hipMemsetAsync(ws, 0, 64, stream);        // zero the ticket counters

  k_prep <<<256, 256, 0, stream>>>(x, w, ws);
  k_r2t0 <<<512, 256, 0, stream>>>(w, ws);
  k_t1   <<<512, 256, 0, stream>>>(w, ws);
  k_final<<<512, 256, 0, stream>>>(out, ws);
}

// Round 8
// 116.037 us; speedup vs baseline: 3.9312x; 1.8084x over previous
//
#include <hip/hip_runtime.h>
#include <math.h>

#define JB   16384
#define FEPS 1e-9f
#define PADX 72     // LDS row stride (ushorts): 144 B, 16B-aligned, <=2-way banks

// ws float offsets — every region fully written before read; NO memset, NO atomics
#define WS_BD0   0        // 64 : B-delta iter 0 [i*8+j]
#define WS_BD1   64       // 64 : B-delta iter 1
#define WS_UMP   128      // 512*64 : u_mean partials [i*64+chunk][d]
#define WS_TP0   32896    // 64*8*64 : t0 partials [rc][j][d]
#define WS_TP1   65664    // 64*8*64 : t1 partials
#define WS_R2V   98432    // 16384*8 : r2[rv][j]  (rv = s*32+b, output row order)
#define WS_X7BV  229504   // 524288 fl (1M ushorts): bf16 x7, rv-order [rv][d]
#define WS_BT    753792   // 16384 fl (32K ushorts): Bt[n][k], n = j*64+e

typedef short short8 __attribute__((ext_vector_type(8)));
typedef float f32x4  __attribute__((ext_vector_type(4)));

static __device__ inline ushort f2bf(float f) {
  union { float f; unsigned u; } a; a.f = f;
  unsigned u = a.u;
  u += 0x7fffu + ((u >> 16) & 1u);   // RNE
  return (ushort)(u >> 16);
}
static __device__ inline float bf2f(ushort h) {
  union { unsigned u; float f; } c; c.u = ((unsigned)h) << 16;
  return c.f;
}

// ---------------------------------------------------------------- k_main
// blocks 0..511  : um-scan of x (i = blk>>6, chunk = blk&63, 256 rows);
//                  i==7 blocks also emit bf16 x7 in rv-order.
// blocks 512..1023: MFMA GEMM (rc = bid>>3, j = bid&7) on fp32 x7 ->
//                  r2[rv][j] + t0 partials (c0 = 1/8); rc==0 blocks store bt.
__global__ __launch_bounds__(256) void k_main(const float* __restrict__ x,
                                              const float* __restrict__ w,
                                              float* __restrict__ ws) {
  int blk = blockIdx.x, t = threadIdx.x;
  __shared__ float4 s4[256];          // scan path (4 KB)
  __shared__ float wl[4096];          // gemm path: w7j stage (16 KB)
  __shared__ ushort x7l[128 * PADX];  // gemm path: bf16 rows (18 KB)
  __shared__ float gs[128];
  __shared__ float red[256];
  ushort* x7bv = (ushort*)(ws + WS_X7BV);
  ushort* bt   = (ushort*)(ws + WS_BT);

  if (blk < 512) {                    // ---------- um-scan path
    int i = blk >> 6, c = blk & 63;
    int q = t & 15, rsub = t >> 4;
    const float4* xr = (const float4*)(x + ((size_t)i * JB + c * 256) * 64);
    float4 a = make_float4(0.f, 0.f, 0.f, 0.f);
    for (int rr = rsub; rr < 256; rr += 16) {
      float4 v = xr[rr * 16 + q];
      a.x += v.x; a.y += v.y; a.z += v.z; a.w += v.w;
      if (i == 7) {                   // uniform branch
        ushort4 h = make_ushort4(f2bf(v.x), f2bf(v.y), f2bf(v.z), f2bf(v.w));
        int rn = c * 256 + rr;
        int rv = ((rn & 511) << 5) | (rn >> 9);   // rv = s*32 + b
        *(ushort4*)(x7bv + (size_t)rv * 64 + q * 4) = h;
      }
    }
    s4[t] = a;
    __syncthreads();
    if (t < 16) {
      float4 s = s4[t];
      for (int k = 1; k < 16; ++k) {
        float4 v = s4[t + k * 16];
        s.x += v.x; s.y += v.y; s.z += v.z; s.w += v.w;
      }
      *(float4*)(ws + WS_UMP + (size_t)blk * 64 + t * 4) = s;
    }
    return;
  }

  // ---------- GEMM path
  int bid = blk - 512;
  int j = bid & 7, rc = bid >> 3, rm0 = rc * 256;
  int lane = t & 63, wv = t >> 6, m = lane & 15, quad = lane >> 4;

  const float* w7j = w + (size_t)(56 + j) * 4096;
  #pragma unroll
  for (int k = 0; k < 16; ++k) wl[t + k * 256] = w7j[t + k * 256];
  __syncthreads();

  short8 bfr[4][2];
  #pragma unroll
  for (int nt = 0; nt < 4; ++nt)
    #pragma unroll
    for (int kb = 0; kb < 2; ++kb) {
      short8 hv;
      #pragma unroll
      for (int u = 0; u < 8; ++u)
        hv[u] = (short)f2bf(wl[(kb * 32 + quad * 8 + u) * 64 + nt * 16 + m]);
      bfr[nt][kb] = hv;
    }
  if (rc == 0) {                      // persist bt for k_out
    #pragma unroll
    for (int nt = 0; nt < 4; ++nt)
      #pragma unroll
      for (int kb = 0; kb < 2; ++kb)
        *(short8*)(bt + ((size_t)j * 64 + nt * 16 + m) * 64 + kb * 32 + quad * 8) = bfr[nt][kb];
  }

  const float* x7 = x + (size_t)7 * JB * 64;
  float tacc = 0.f;
  #pragma unroll
  for (int h = 0; h < 2; ++h) {
    #pragma unroll
    for (int s = 0; s < 2; ++s) {
      int rb = rm0 + h * 128 + s * 64 + wv * 16;
      const float* ap = x7 + (size_t)(rb + m) * 64;
      float4 f0 = *(const float4*)(ap + quad * 8);
      float4 f1 = *(const float4*)(ap + quad * 8 + 4);
      float4 f2 = *(const float4*)(ap + 32 + quad * 8);
      float4 f3 = *(const float4*)(ap + 32 + quad * 8 + 4);
      short8 a0, a1;
      a0[0] = (short)f2bf(f0.x); a0[1] = (short)f2bf(f0.y);
      a0[2] = (short)f2bf(f0.z); a0[3] = (short)f2bf(f0.w);
      a0[4] = (short)f2bf(f1.x); a0[5] = (short)f2bf(f1.y);
      a0[6] = (short)f2bf(f1.z); a0[7] = (short)f2bf(f1.w);
      a1[0] = (short)f2bf(f2.x); a1[1] = (short)f2bf(f2.y);
      a1[2] = (short)f2bf(f2.z); a1[3] = (short)f2bf(f2.w);
      a1[4] = (short)f2bf(f3.x); a1[5] = (short)f2bf(f3.y);
      a1[6] = (short)f2bf(f3.z); a1[7] = (short)f2bf(f3.w);
      int lrow = s * 64 + wv * 16 + m;
      *(short8*)(x7l + lrow * PADX + quad * 8) = a0;        // stage for t0
      *(short8*)(x7l + lrow * PADX + 32 + quad * 8) = a1;

      f32x4 acc[4];
      #pragma unroll
      for (int nt = 0; nt < 4; ++nt) acc[nt] = (f32x4){0.f, 0.f, 0.f, 0.f};
      #pragma unroll
      for (int nt = 0; nt < 4; ++nt) {
        acc[nt] = __builtin_amdgcn_mfma_f32_16x16x32_bf16(a0, bfr[nt][0], acc[nt], 0, 0, 0);
        acc[nt] = __builtin_amdgcn_mfma_f32_16x16x32_bf16(a1, bfr[nt][1], acc[nt], 0, 0, 0);
      }
      float sq[4];
      #pragma unroll
      for (int r = 0; r < 4; ++r)
        sq[r] = acc[0][r] * acc[0][r] + acc[1][r] * acc[1][r] +
                acc[2][r] * acc[2][r] + acc[3][r] * acc[3][r];
      #pragma unroll
      for (int mk = 1; mk < 16; mk <<= 1) {
        #pragma unroll
        for (int r = 0; r < 4; ++r) sq[r] += __shfl_xor(sq[r], mk, 64);
      }
      if (m == 0) {
        #pragma unroll
        for (int r = 0; r < 4; ++r) {
          int rn = rb + quad * 4 + r;
          int rv = ((rn & 511) << 5) | (rn >> 9);
          ws[WS_R2V + (size_t)rv * 8 + j] = sq[r];          // rv-order store
          float s2 = 0.015625f * sq[r];                     // (1/8)^2 * r2
          gs[s * 64 + wv * 16 + quad * 4 + r] =
              0.125f * s2 / ((1.f + s2) * sqrtf(s2 + FEPS));
        }
      }
    }
    __syncthreads();
    {
      int d = lane;
      float a = 0.f;
      #pragma unroll 8
      for (int r = 0; r < 32; ++r) {
        int row = wv * 32 + r;
        a += gs[row] * bf2f(x7l[row * PADX + d]);
      }
      tacc += a;
    }
    __syncthreads();
  }
  red[t] = tacc;
  __syncthreads();
  if (t < 64)
    ws[WS_TP0 + (size_t)(rc * 8 + j) * 64 + t] =
        red[t] + red[t + 64] + red[t + 128] + red[t + 192];
}

// ---------------------------------------------------------------- k_bd
// Bd[i][j] = (1/JB^2) * um[i] . ( W[i][j] . ( W7[j]^T-contraction of t[j] ) )
// (identical to uhm-based formula by reassociation; Bd magnitudes ~1e-5,
//  output is ultra-insensitive to this value's rounding)
template <int PASS>
__global__ __launch_bounds__(128) void k_bd(const float* __restrict__ w,
                                            float* __restrict__ ws) {
  int i = blockIdx.x >> 3, j = blockIdx.x & 7;
  int t = threadIdx.x;
  __shared__ float tls[64], uml[64], vml[64], part[64];
  const float* tp = ws + (PASS == 0 ? WS_TP0 : WS_TP1);
  if (t < 64) {
    float s = 0.f;
    #pragma unroll 8
    for (int c = 0; c < 64; ++c) s += tp[(size_t)(c * 8 + j) * 64 + t];
    tls[t] = s;
  } else {
    int d = t - 64;
    float s = 0.f;
    #pragma unroll 8
    for (int c = 0; c < 64; ++c) s += ws[WS_UMP + (size_t)(i * 64 + c) * 64 + d];
    uml[d] = s;
  }
  __syncthreads();
  if (t < 64) {
    const float* w7j = w + (size_t)(56 + j) * 4096;
    float acc = 0.f;
    for (int d = 0; d < 64; ++d) acc += w7j[d * 64 + t] * tls[d];
    vml[t] = acc * (1.0f / (float)JB);
  }
  __syncthreads();
  if (t < 64) {
    const float* wij = w + (size_t)(i * 8 + j) * 4096;
    float acc = 0.f;
    for (int e = 0; e < 64; ++e) acc += wij[t * 64 + e] * vml[e];
    part[t] = uml[t] * acc;
  }
  __syncthreads();
  if (t == 0) {
    float s = 0.f;
    for (int d = 0; d < 64; ++d) s += part[d];
    ws[(PASS == 0 ? WS_BD0 : WS_BD1) + i * 8 + j] = s * (1.0f / (float)JB);
  }
}

// ---------------------------------------------------------------- k_t1
// t1 partials; c1 = softmax(Bd0) col j computed inline (8 loads + 8 exp)
__global__ __launch_bounds__(256) void k_t1(float* __restrict__ ws) {
  int t = threadIdx.x, blk = blockIdx.x;
  int lane = t & 63, wv = t >> 6;
  int j = blk & 7, rc = blk >> 3, rm0 = rc * 256;
  __shared__ ushort x7l[128 * PADX];
  __shared__ float gs[128];
  __shared__ float red[256];
  __shared__ float cl;
  ushort* x7bv = (ushort*)(ws + WS_X7BV);
  if (t == 0) {
    float bv[8], mx = -1e30f;
    for (int i = 0; i < 8; ++i) { bv[i] = ws[WS_BD0 + i * 8 + j]; mx = fmaxf(mx, bv[i]); }
    float ss = 0.f;
    for (int i = 0; i < 8; ++i) ss += expf(bv[i] - mx);
    cl = expf(bv[7] - mx) / ss;
  }
  __syncthreads();
  float c1 = cl;
  float tacc = 0.f;
  #pragma unroll
  for (int h = 0; h < 2; ++h) {
    int rbh = rm0 + h * 128;
    #pragma unroll
    for (int k = 0; k < 4; ++k) {
      int c16 = t + k * 256;
      int row = c16 >> 3, seg = c16 & 7;
      *(short8*)(x7l + row * PADX + seg * 8) =
          *(const short8*)(x7bv + (size_t)(rbh + row) * 64 + seg * 8);
    }
    if (t < 128) {
      float r2v = ws[WS_R2V + (size_t)(rbh + t) * 8 + j];
      float s2 = c1 * c1 * r2v;
      gs[t] = c1 * s2 / ((1.f + s2) * sqrtf(s2 + FEPS));
    }
    __syncthreads();
    {
      int d = lane;
      float a = 0.f;
      #pragma unroll 8
      for (int r = 0; r < 32; ++r) {
        int row = wv * 32 + r;
        a += gs[row] * bf2f(x7l[row * PADX + d]);
      }
      tacc += a;
    }
    __syncthreads();
  }
  red[t] = tacc;
  __syncthreads();
  if (t < 64)
    ws[WS_TP1 + (size_t)(rc * 8 + j) * 64 + t] =
        red[t] + red[t + 64] + red[t + 128] + red[t + 192];
}

// ---------------------------------------------------------------- k_out
// cf = softmax(Bd0+Bd1) inline; out[j][rv][e] = g(cf, r2) * p  (rv-order)
__global__ __launch_bounds__(256) void k_out(float* __restrict__ out,
                                             float* __restrict__ ws) {
  int t = threadIdx.x, blk = blockIdx.x;
  int lane = t & 63, wv = t >> 6, m = lane & 15, quad = lane >> 4;
  int j = blk & 7, rc = blk >> 3, rm0 = rc * 256;
  __shared__ float cl;
  ushort* x7bv = (ushort*)(ws + WS_X7BV);
  ushort* bt   = (ushort*)(ws + WS_BT);
  if (t == 0) {
    float bv[8], mx = -1e30f;
    for (int i = 0; i < 8; ++i) {
      bv[i] = ws[WS_BD0 + i * 8 + j] + ws[WS_BD1 + i * 8 + j];
      mx = fmaxf(mx, bv[i]);
    }
    float ss = 0.f;
    for (int i = 0; i < 8; ++i) ss += expf(bv[i] - mx);
    cl = expf(bv[7] - mx) / ss;
  }
  __syncthreads();
  float cf = cl;

  short8 bfr[4][2];
  const ushort* btj = bt + (size_t)(j * 64) * 64;
  #pragma unroll
  for (int nt = 0; nt < 4; ++nt)
    #pragma unroll
    for (int kb = 0; kb < 2; ++kb)
      bfr[nt][kb] = *(const short8*)(btj + (size_t)(nt * 16 + m) * 64 + kb * 32 + quad * 8);

  #pragma unroll
  for (int h = 0; h < 2; ++h) {
    #pragma unroll
    for (int s = 0; s < 2; ++s) {
      int rb = rm0 + h * 128 + s * 64 + wv * 16;   // rv-order rows
      const ushort* ap = x7bv + (size_t)(rb + m) * 64 + quad * 8;
      short8 a0 = *(const short8*)ap;
      short8 a1 = *(const short8*)(ap + 32);
      f32x4 acc[4];
      #pragma unroll
      for (int nt = 0; nt < 4; ++nt) acc[nt] = (f32x4){0.f, 0.f, 0.f, 0.f};
      #pragma unroll
      for (int nt = 0; nt < 4; ++nt) {
        acc[nt] = __builtin_amdgcn_mfma_f32_16x16x32_bf16(a0, bfr[nt][0], acc[nt], 0, 0, 0);
        acc[nt] = __builtin_amdgcn_mfma_f32_16x16x32_bf16(a1, bfr[nt][1], acc[nt], 0, 0, 0);
      }
      float sq[4];
      #pragma unroll
      for (int r = 0; r < 4; ++r)
        sq[r] = acc[0][r] * acc[0][r] + acc[1][r] * acc[1][r] +
                acc[2][r] * acc[2][r] + acc[3][r] * acc[3][r];
      #pragma unroll
      for (int mk = 1; mk < 16; mk <<= 1) {
        #pragma unroll
        for (int r = 0; r < 4; ++r) sq[r] += __shfl_xor(sq[r], mk, 64);
      }
      #pragma unroll
      for (int r = 0; r < 4; ++r) {
        float s2 = cf * cf * sq[r];
        float g = cf * s2 / ((1.f + s2) * sqrtf(s2 + FEPS));
        size_t base = ((size_t)j * JB + (rb + quad * 4 + r)) * 64;
        #pragma unroll
        for (int nt = 0; nt < 4; ++nt)
          out[base + nt * 16 + m] = g * acc[nt][r];
      }
    }
  }
}

extern "C" void kernel_launch(void* const* d_in, const int* in_sizes, int n_in,
                              void* d_out, int out_size, void* d_ws, size_t ws_size,
                              hipStream_t stream) {
  const float* x = (const float*)d_in[0];   // (8,32,512,64) f32
  const float* w = (const float*)d_in[1];   // (8,8,64,64)  f32
  float* out = (float*)d_out;               // (8,32,512,64) f32
  float* ws = (float*)d_ws;

  k_main <<<1024, 256, 0, stream>>>(x, w, ws);
  k_bd<0><<<64,   128, 0, stream>>>(w, ws);
  k_t1   <<<512,  256, 0, stream>>>(ws);
  k_bd<1><<<64,   128, 0, stream>>>(w, ws);
  k_out  <<<512,  256, 0, stream>>>(out, ws);
}